// Round 1
// baseline (639.864 us; speedup 1.0000x reference)
//
#include <hip/hip_runtime.h>
#include <hip/hip_bf16.h>

typedef float  f32x4  __attribute__((ext_vector_type(4)));
typedef short  s16x4  __attribute__((ext_vector_type(4)));
typedef short  s16x8  __attribute__((ext_vector_type(8)));
typedef __bf16 bf16x8 __attribute__((ext_vector_type(8)));

#define N_PIX 4096

__device__ __forceinline__ unsigned short f2bf(float f) {
    __hip_bfloat16 h = __float2bfloat16(f);
    return *reinterpret_cast<unsigned short*>(&h);
}
__device__ __forceinline__ float bf2f(unsigned short u) {
    __hip_bfloat16 h;
    *reinterpret_cast<unsigned short*>(&h) = u;
    return __bfloat162float(h);
}

// ---- MFMA wrappers: prefer K=16 classic (layout certain), fall back to K=32 ----
#if __has_builtin(__builtin_amdgcn_mfma_f32_16x16x16bf16_1k)
#define USE_K16 1
#else
#define USE_K16 0
#endif

// Accumulate a K=32 block. alo/ahi are the two 4-element (c 0..15 / c 16..31,
// pattern k = 16*half + 4*(lane>>4) + j) halves of the A fragment, same for b.
__device__ __forceinline__ f32x4 mac_k32(s16x4 alo, s16x4 ahi, s16x4 blo, s16x4 bhi, f32x4 c) {
#if USE_K16
    c = __builtin_amdgcn_mfma_f32_16x16x16bf16_1k(alo, blo, c, 0, 0, 0);
    c = __builtin_amdgcn_mfma_f32_16x16x16bf16_1k(ahi, bhi, c, 0, 0, 0);
#else
    s16x8 a8 = __builtin_shufflevector(alo, ahi, 0, 1, 2, 3, 4, 5, 6, 7);
    s16x8 b8 = __builtin_shufflevector(blo, bhi, 0, 1, 2, 3, 4, 5, 6, 7);
    c = __builtin_amdgcn_mfma_f32_16x16x32_bf16(__builtin_bit_cast(bf16x8, a8),
                                                __builtin_bit_cast(bf16x8, b8), c, 0, 0, 0);
#endif
    return c;
}

// ---- x -> bf16 copy (v operand for PV matmul) ----
__global__ __launch_bounds__(256) void to_bf16_kernel(const float* __restrict__ x,
                                                      unsigned short* __restrict__ v_bf) {
    int i = blockIdx.x * 256 + threadIdx.x;   // exactly 4*64*4096 = 1048576 threads
    v_bf[i] = f2bf(x[i]);
}

// ---- conv3x3 (q and k), direct f32, writes transposed hi/lo bf16 [d][n][32] ----
__global__ __launch_bounds__(256) void conv_qk_kernel(
    const float* __restrict__ x,
    const float* __restrict__ q_w, const float* __restrict__ q_b,
    const float* __restrict__ k_w, const float* __restrict__ k_b,
    unsigned short* __restrict__ qTp_hi, unsigned short* __restrict__ qTp_lo,
    unsigned short* __restrict__ kTp_hi, unsigned short* __restrict__ kTp_lo) {
    __shared__ float qw_s[576];
    __shared__ float kw_s[576];
    int bid = blockIdx.x;
    int d  = bid >> 9;          // 512 blocks per d
    int o  = (bid >> 4) & 31;   // output channel (fixed per block -> uniform weights)
    int yg = bid & 15;          // group of 4 rows
    int tid = threadIdx.x;
    for (int i = tid; i < 576; i += 256) {
        qw_s[i] = q_w[o * 576 + i];
        kw_s[i] = k_w[o * 576 + i];
    }
    __syncthreads();
    int y   = yg * 4 + (tid >> 6);
    int col = tid & 63;
    const float* xd = x + (size_t)d * (64 * N_PIX);
    float aq = q_b[o];
    float ak = k_b[o];
    for (int c = 0; c < 64; ++c) {
        const float* xc = xd + c * N_PIX;
        const float* wq = &qw_s[c * 9];
        const float* wk = &kw_s[c * 9];
#pragma unroll
        for (int dy = 0; dy < 3; ++dy) {
            int yy = y + dy - 1;
            bool rok = ((unsigned)yy < 64u);
            int rb = yy * 64;
            float x0 = (rok && col >= 1)  ? xc[rb + col - 1] : 0.f;
            float x1 = rok                ? xc[rb + col]     : 0.f;
            float x2 = (rok && col <= 62) ? xc[rb + col + 1] : 0.f;
            aq += wq[dy * 3 + 0] * x0 + wq[dy * 3 + 1] * x1 + wq[dy * 3 + 2] * x2;
            ak += wk[dy * 3 + 0] * x0 + wk[dy * 3 + 1] * x1 + wk[dy * 3 + 2] * x2;
        }
    }
    int n = y * 64 + col;
    size_t base = ((size_t)d * N_PIX + n) * 32 + o;
    unsigned short qh = f2bf(aq);
    unsigned short ql = f2bf(aq - bf2f(qh));
    unsigned short kh = f2bf(ak);
    unsigned short kl = f2bf(ak - bf2f(kh));
    qTp_hi[base] = qh; qTp_lo[base] = ql;
    kTp_hi[base] = kh; kTp_lo[base] = kl;
}

// ---- fused double-softmax attention: one wave handles 16 query rows ----
// S^T orientation: MFMA D rows = m (4*(l>>4)+r within 16-tile), cols = n (l&15).
__global__ __launch_bounds__(64) void attn_kernel(
    const float* __restrict__ x, const float* __restrict__ atten,
    const float* __restrict__ gamma,
    const unsigned short* __restrict__ qTp_hi, const unsigned short* __restrict__ qTp_lo,
    const unsigned short* __restrict__ kTp_hi, const unsigned short* __restrict__ kTp_lo,
    const unsigned short* __restrict__ v_bf, float* __restrict__ out) {
    __shared__ __align__(16) unsigned short P_s[16][68];   // bf16 P tile, padded

    int lane = threadIdx.x;
    int n16 = lane & 15;
    int g   = lane >> 4;
    int bid = blockIdx.x;
    int d   = bid >> 8;
    int rb  = (bid & 255) << 4;      // first of this wave's 16 query rows
    int nrow = rb + n16;

    // q fragments (B operand), fixed for whole kernel
    size_t qrow = ((size_t)d * N_PIX + nrow) * 32;
    s16x4 qh0 = *(const s16x4*)(qTp_hi + qrow + 4 * g);
    s16x4 qh1 = *(const s16x4*)(qTp_hi + qrow + 16 + 4 * g);
    s16x4 ql0 = *(const s16x4*)(qTp_lo + qrow + 4 * g);
    s16x4 ql1 = *(const s16x4*)(qTp_lo + qrow + 16 + 4 * g);

    const unsigned short* kTh_d = kTp_hi + (size_t)d * N_PIX * 32;
    const unsigned short* kTl_d = kTp_lo + (size_t)d * N_PIX * 32;

    // ---------- phase A: L1 = sum_m exp(S - 40) for this lane's row ----------
    float L1 = 0.f;
    for (int m0 = 0; m0 < N_PIX; m0 += 64) {
        float part = 0.f;
#pragma unroll
        for (int t = 0; t < 4; ++t) {
            size_t krow = (size_t)(m0 + t * 16 + n16) * 32;
            s16x4 kh0 = *(const s16x4*)(kTh_d + krow + 4 * g);
            s16x4 kh1 = *(const s16x4*)(kTh_d + krow + 16 + 4 * g);
            s16x4 kl0 = *(const s16x4*)(kTl_d + krow + 4 * g);
            s16x4 kl1 = *(const s16x4*)(kTl_d + krow + 16 + 4 * g);
            f32x4 s = {0.f, 0.f, 0.f, 0.f};
            s = mac_k32(kh0, kh1, qh0, qh1, s);
            s = mac_k32(kh0, kh1, ql0, ql1, s);
            s = mac_k32(kl0, kl1, qh0, qh1, s);
            part += __expf(s[0] - 40.f) + __expf(s[1] - 40.f) +
                    __expf(s[2] - 40.f) + __expf(s[3] - 40.f);
        }
        part += __shfl_xor(part, 16, 64);
        part += __shfl_xor(part, 32, 64);
        L1 += part;
    }
    float rcpL1 = 1.f / L1;

    // ---------- phase B: second softmax (fixed shift 8) + PV accumulation ----------
    const float* arow = atten + ((size_t)d << 24) + (size_t)nrow * N_PIX;
    const unsigned short* v_d = v_bf + (size_t)d * 64 * N_PIX;
    float L2 = 0.f;
    f32x4 acco[4];
#pragma unroll
    for (int ct = 0; ct < 4; ++ct) acco[ct] = f32x4{0.f, 0.f, 0.f, 0.f};

    for (int m0 = 0; m0 < N_PIX; m0 += 64) {
        // atten gather (per-lane row = n16, L1-served)
        float av[4][4];
#pragma unroll
        for (int t = 0; t < 4; ++t)
#pragma unroll
            for (int r = 0; r < 4; ++r)
                av[t][r] = arow[m0 + t * 16 + g * 4 + r];

        float part = 0.f;
#pragma unroll
        for (int t = 0; t < 4; ++t) {
            size_t krow = (size_t)(m0 + t * 16 + n16) * 32;
            s16x4 kh0 = *(const s16x4*)(kTh_d + krow + 4 * g);
            s16x4 kh1 = *(const s16x4*)(kTh_d + krow + 16 + 4 * g);
            s16x4 kl0 = *(const s16x4*)(kTl_d + krow + 4 * g);
            s16x4 kl1 = *(const s16x4*)(kTl_d + krow + 16 + 4 * g);
            f32x4 s = {0.f, 0.f, 0.f, 0.f};
            s = mac_k32(kh0, kh1, qh0, qh1, s);
            s = mac_k32(kh0, kh1, ql0, ql1, s);
            s = mac_k32(kl0, kl1, qh0, qh1, s);
#pragma unroll
            for (int r = 0; r < 4; ++r) {
                float attn1 = __expf(s[r] - 40.f) * rcpL1;
                float p = __expf(attn1 + av[t][r] - 8.f);
                part += p;
                P_s[n16][t * 16 + 4 * g + r] = f2bf(p);
            }
        }
        part += __shfl_xor(part, 16, 64);
        part += __shfl_xor(part, 32, 64);
        L2 += part;

        asm volatile("" ::: "memory");   // order LDS writes before reads (same wave)

        // PV: out[c][n] += sum_m P[n][m] * v[c][m], two K=32 halves
#pragma unroll
        for (int h = 0; h < 2; ++h) {
            s16x4 p0 = *(const s16x4*)&P_s[n16][h * 32 + 4 * g];
            s16x4 p1 = *(const s16x4*)&P_s[n16][h * 32 + 16 + 4 * g];
#pragma unroll
            for (int ct = 0; ct < 4; ++ct) {
                const unsigned short* vr = v_d + (size_t)(ct * 16 + n16) * N_PIX + m0 + h * 32;
                s16x4 v0 = *(const s16x4*)(vr + 4 * g);
                s16x4 v1 = *(const s16x4*)(vr + 16 + 4 * g);
                acco[ct] = mac_k32(v0, v1, p0, p1, acco[ct]);
            }
        }
        asm volatile("" ::: "memory");   // keep next chunk's LDS writes after these reads
    }

    // ---------- epilogue ----------
    float rcpL2 = 1.f / L2;
    float gam = gamma[0];
#pragma unroll
    for (int ct = 0; ct < 4; ++ct) {
#pragma unroll
        for (int r = 0; r < 4; ++r) {
            int c = ct * 16 + 4 * g + r;
            size_t idx = ((size_t)(d * 64 + c)) * N_PIX + rb + n16;
            out[idx] = gam * acco[ct][r] * rcpL2 + x[idx];
        }
    }
}

extern "C" void kernel_launch(void* const* d_in, const int* in_sizes, int n_in,
                              void* d_out, int out_size, void* d_ws, size_t ws_size,
                              hipStream_t stream) {
    const float* x     = (const float*)d_in[0];
    const float* atten = (const float*)d_in[1];
    const float* q_w   = (const float*)d_in[2];
    const float* q_b   = (const float*)d_in[3];
    const float* k_w   = (const float*)d_in[4];
    const float* k_b   = (const float*)d_in[5];
    const float* gamma = (const float*)d_in[6];
    float* out = (float*)d_out;

    char* ws = (char*)d_ws;
    const size_t MB = 1u << 20;
    unsigned short* qTp_hi = (unsigned short*)(ws + 0 * MB);   // [4][4096][32] bf16
    unsigned short* qTp_lo = (unsigned short*)(ws + 1 * MB);
    unsigned short* kTp_hi = (unsigned short*)(ws + 2 * MB);
    unsigned short* kTp_lo = (unsigned short*)(ws + 3 * MB);
    unsigned short* v_bf   = (unsigned short*)(ws + 4 * MB);   // [4][64][4096] bf16 (2 MB)

    hipLaunchKernelGGL(to_bf16_kernel, dim3(4096), dim3(256), 0, stream, x, v_bf);
    hipLaunchKernelGGL(conv_qk_kernel, dim3(2048), dim3(256), 0, stream,
                       x, q_w, q_b, k_w, k_b, qTp_hi, qTp_lo, kTp_hi, kTp_lo);
    hipLaunchKernelGGL(attn_kernel, dim3(1024), dim3(64), 0, stream,
                       x, atten, gamma, qTp_hi, qTp_lo, kTp_hi, kTp_lo, v_bf, out);
}

// Round 2
// 603.311 us; speedup vs baseline: 1.0606x; 1.0606x over previous
//
#include <hip/hip_runtime.h>
#include <hip/hip_bf16.h>

typedef float  f32x4  __attribute__((ext_vector_type(4)));
typedef short  s16x4  __attribute__((ext_vector_type(4)));
typedef short  s16x8  __attribute__((ext_vector_type(8)));
typedef __bf16 bf16x8 __attribute__((ext_vector_type(8)));

#define N_PIX 4096

__device__ __forceinline__ unsigned short f2bf(float f) {
    __hip_bfloat16 h = __float2bfloat16(f);
    return *reinterpret_cast<unsigned short*>(&h);
}
__device__ __forceinline__ float bf2f(unsigned short u) {
    __hip_bfloat16 h;
    *reinterpret_cast<unsigned short*>(&h) = u;
    return __bfloat162float(h);
}

// ---- MFMA wrappers: prefer K=16 classic (layout certain), fall back to K=32 ----
#if __has_builtin(__builtin_amdgcn_mfma_f32_16x16x16bf16_1k)
#define USE_K16 1
#else
#define USE_K16 0
#endif

__device__ __forceinline__ f32x4 mac_k32(s16x4 alo, s16x4 ahi, s16x4 blo, s16x4 bhi, f32x4 c) {
#if USE_K16
    c = __builtin_amdgcn_mfma_f32_16x16x16bf16_1k(alo, blo, c, 0, 0, 0);
    c = __builtin_amdgcn_mfma_f32_16x16x16bf16_1k(ahi, bhi, c, 0, 0, 0);
#else
    s16x8 a8 = __builtin_shufflevector(alo, ahi, 0, 1, 2, 3, 4, 5, 6, 7);
    s16x8 b8 = __builtin_shufflevector(blo, bhi, 0, 1, 2, 3, 4, 5, 6, 7);
    c = __builtin_amdgcn_mfma_f32_16x16x32_bf16(__builtin_bit_cast(bf16x8, a8),
                                                __builtin_bit_cast(bf16x8, b8), c, 0, 0, 0);
#endif
    return c;
}

// ---- x -> bf16 copy (v operand for PV matmul) ----
__global__ __launch_bounds__(256) void to_bf16_kernel(const float* __restrict__ x,
                                                      unsigned short* __restrict__ v_bf) {
    int i = blockIdx.x * 256 + threadIdx.x;   // exactly 4*64*4096 = 1048576 threads
    v_bf[i] = f2bf(x[i]);
}

// ---- zero-pad x into xp[4][64][66][66] (removes ALL conv boundary branches) ----
__global__ __launch_bounds__(256) void pad_kernel(const float* __restrict__ x,
                                                  float* __restrict__ xp) {
    int i = blockIdx.x * 256 + threadIdx.x;   // exactly 4*64*66*66 = 1115136 threads
    int xx = i % 66;
    int t  = i / 66;
    int yy = t % 66;
    int cd = t / 66;                           // cd = d*64 + c
    float v = 0.f;
    if (xx >= 1 && xx <= 64 && yy >= 1 && yy <= 64)
        v = x[(size_t)cd * 4096 + (yy - 1) * 64 + (xx - 1)];
    xp[i] = v;
}

// ---- conv3x3 (q and k) on padded input: branch-free, SGPR weights ----
__global__ __launch_bounds__(256) void conv_qk_kernel(
    const float* __restrict__ xp,
    const float* __restrict__ q_w, const float* __restrict__ q_b,
    const float* __restrict__ k_w, const float* __restrict__ k_b,
    unsigned short* __restrict__ qTp_hi, unsigned short* __restrict__ qTp_lo,
    unsigned short* __restrict__ kTp_hi, unsigned short* __restrict__ kTp_lo) {
    int bid = blockIdx.x;
    int d  = bid >> 9;                                         // 512 blocks per d
    int o  = __builtin_amdgcn_readfirstlane((bid >> 4) & 31);  // uniform out-channel
    int yg = bid & 15;
    int tid = threadIdx.x;
    int y   = yg * 4 + (tid >> 6);
    int col = tid & 63;
    const float* xc0 = xp + (size_t)d * (64 * 4356) + y * 66 + col; // 3x3 patch top-left
    const float* wq = q_w + o * 576;
    const float* wk = k_w + o * 576;
    float aq0 = 0.f, aq1 = 0.f, aq2 = 0.f, ak0 = 0.f, ak1 = 0.f, ak2 = 0.f;
#pragma unroll 2
    for (int c = 0; c < 64; ++c) {
        const float* xc = xc0 + c * 4356;
        float x00 = xc[0],   x01 = xc[1],   x02 = xc[2];
        float x10 = xc[66],  x11 = xc[67],  x12 = xc[68];
        float x20 = xc[132], x21 = xc[133], x22 = xc[134];
        const float* wqc = wq + c * 9;
        const float* wkc = wk + c * 9;
        aq0 = fmaf(wqc[0], x00, fmaf(wqc[1], x01, fmaf(wqc[2], x02, aq0)));
        aq1 = fmaf(wqc[3], x10, fmaf(wqc[4], x11, fmaf(wqc[5], x12, aq1)));
        aq2 = fmaf(wqc[6], x20, fmaf(wqc[7], x21, fmaf(wqc[8], x22, aq2)));
        ak0 = fmaf(wkc[0], x00, fmaf(wkc[1], x01, fmaf(wkc[2], x02, ak0)));
        ak1 = fmaf(wkc[3], x10, fmaf(wkc[4], x11, fmaf(wkc[5], x12, ak1)));
        ak2 = fmaf(wkc[6], x20, fmaf(wkc[7], x21, fmaf(wkc[8], x22, ak2)));
    }
    float aq = aq0 + aq1 + aq2 + q_b[o];
    float ak = ak0 + ak1 + ak2 + k_b[o];
    int n = y * 64 + col;
    size_t base = ((size_t)d * N_PIX + n) * 32 + o;
    unsigned short qh = f2bf(aq);
    unsigned short ql = f2bf(aq - bf2f(qh));
    unsigned short kh = f2bf(ak);
    unsigned short kl = f2bf(ak - bf2f(kh));
    qTp_hi[base] = qh; qTp_lo[base] = ql;
    kTp_hi[base] = kh; kTp_lo[base] = kl;
}

// ---- fused double-softmax attention: 4 waves/block, m-split across waves ----
// S^T orientation: MFMA D rows = m (4*(l>>4)+r within 16-tile), cols = n (l&15).
__global__ __launch_bounds__(256) void attn_kernel(
    const float* __restrict__ x, const float* __restrict__ atten,
    const float* __restrict__ gamma,
    const unsigned short* __restrict__ qTp_hi, const unsigned short* __restrict__ qTp_lo,
    const unsigned short* __restrict__ kTp_hi, const unsigned short* __restrict__ kTp_lo,
    const unsigned short* __restrict__ v_bf, float* __restrict__ out) {
    __shared__ __align__(16) unsigned short P_s[4][16][68];  // per-wave P tile
    __shared__ float Lred[4][16];                            // L1 then L2 row partials
    __shared__ float Ared[4][64][17];                        // acc cross-wave reduce

    int tid  = threadIdx.x;
    int lane = tid & 63;
    int w    = tid >> 6;
    int n16 = lane & 15;
    int g   = lane >> 4;
    int bid = blockIdx.x;
    int d   = bid >> 8;
    int rb  = (bid & 255) << 4;      // first of this block's 16 query rows
    int nrow = rb + n16;

    // q fragments (B operand), fixed for whole kernel
    size_t qrow = ((size_t)d * N_PIX + nrow) * 32;
    s16x4 qh0 = *(const s16x4*)(qTp_hi + qrow + 4 * g);
    s16x4 qh1 = *(const s16x4*)(qTp_hi + qrow + 16 + 4 * g);
    s16x4 ql0 = *(const s16x4*)(qTp_lo + qrow + 4 * g);
    s16x4 ql1 = *(const s16x4*)(qTp_lo + qrow + 16 + 4 * g);

    const unsigned short* kTh_d = kTp_hi + (size_t)d * N_PIX * 32;
    const unsigned short* kTl_d = kTp_lo + (size_t)d * N_PIX * 32;

    // ---------- phase A: L1 = sum_m exp(S - 40), wave w owns chunks (i*4+w) ----------
    float l1p = 0.f;
    for (int i = 0; i < 16; ++i) {
        int m0 = (i * 4 + w) * 64;
#pragma unroll
        for (int t = 0; t < 4; ++t) {
            size_t krow = (size_t)(m0 + t * 16 + n16) * 32;
            s16x4 kh0 = *(const s16x4*)(kTh_d + krow + 4 * g);
            s16x4 kh1 = *(const s16x4*)(kTh_d + krow + 16 + 4 * g);
            s16x4 kl0 = *(const s16x4*)(kTl_d + krow + 4 * g);
            s16x4 kl1 = *(const s16x4*)(kTl_d + krow + 16 + 4 * g);
            f32x4 s = {0.f, 0.f, 0.f, 0.f};
            s = mac_k32(kh0, kh1, qh0, qh1, s);
            s = mac_k32(kh0, kh1, ql0, ql1, s);
            s = mac_k32(kl0, kl1, qh0, qh1, s);
            l1p += __expf(s[0] - 40.f) + __expf(s[1] - 40.f) +
                   __expf(s[2] - 40.f) + __expf(s[3] - 40.f);
        }
    }
    l1p += __shfl_xor(l1p, 16, 64);
    l1p += __shfl_xor(l1p, 32, 64);
    if (g == 0) Lred[w][n16] = l1p;
    __syncthreads();
    float L1 = Lred[0][n16] + Lred[1][n16] + Lred[2][n16] + Lred[3][n16];
    float rcpL1 = 1.f / L1;

    // ---------- phase B: second softmax (fixed shift 8) + PV accumulation ----------
    const float* arow = atten + ((size_t)d << 24) + (size_t)nrow * N_PIX;
    const unsigned short* v_d = v_bf + (size_t)d * 64 * N_PIX;
    float l2p = 0.f;
    f32x4 acco[4];
#pragma unroll
    for (int ct = 0; ct < 4; ++ct) acco[ct] = f32x4{0.f, 0.f, 0.f, 0.f};

    for (int i = 0; i < 16; ++i) {
        int m0 = (i * 4 + w) * 64;
        f32x4 av4[4];
#pragma unroll
        for (int t = 0; t < 4; ++t)
            av4[t] = *(const f32x4*)&arow[m0 + t * 16 + 4 * g];

#pragma unroll
        for (int t = 0; t < 4; ++t) {
            size_t krow = (size_t)(m0 + t * 16 + n16) * 32;
            s16x4 kh0 = *(const s16x4*)(kTh_d + krow + 4 * g);
            s16x4 kh1 = *(const s16x4*)(kTh_d + krow + 16 + 4 * g);
            s16x4 kl0 = *(const s16x4*)(kTl_d + krow + 4 * g);
            s16x4 kl1 = *(const s16x4*)(kTl_d + krow + 16 + 4 * g);
            f32x4 s = {0.f, 0.f, 0.f, 0.f};
            s = mac_k32(kh0, kh1, qh0, qh1, s);
            s = mac_k32(kh0, kh1, ql0, ql1, s);
            s = mac_k32(kl0, kl1, qh0, qh1, s);
#pragma unroll
            for (int r = 0; r < 4; ++r) {
                float attn1 = __expf(s[r] - 40.f) * rcpL1;
                float p = __expf(attn1 + av4[t][r] - 8.f);
                l2p += p;
                P_s[w][n16][t * 16 + 4 * g + r] = f2bf(p);
            }
        }
        asm volatile("" ::: "memory");   // order LDS writes before reads (same wave)

        // PV: out[c][n] += sum_m P[n][m] * v[c][m], two K=32 halves
#pragma unroll
        for (int h = 0; h < 2; ++h) {
            s16x4 p0 = *(const s16x4*)&P_s[w][n16][h * 32 + 4 * g];
            s16x4 p1 = *(const s16x4*)&P_s[w][n16][h * 32 + 16 + 4 * g];
#pragma unroll
            for (int ct = 0; ct < 4; ++ct) {
                const unsigned short* vr = v_d + (size_t)(ct * 16 + n16) * N_PIX + m0 + h * 32;
                s16x4 v0 = *(const s16x4*)(vr + 4 * g);
                s16x4 v1 = *(const s16x4*)(vr + 16 + 4 * g);
                acco[ct] = mac_k32(v0, v1, p0, p1, acco[ct]);
            }
        }
        asm volatile("" ::: "memory");   // keep next chunk's LDS writes after these reads
    }

    // ---------- cross-wave reduction + epilogue ----------
    __syncthreads();                     // Lred reuse safe
    l2p += __shfl_xor(l2p, 16, 64);
    l2p += __shfl_xor(l2p, 32, 64);
    if (g == 0) Lred[w][n16] = l2p;
#pragma unroll
    for (int ct = 0; ct < 4; ++ct)
#pragma unroll
        for (int r = 0; r < 4; ++r)
            Ared[w][lane][ct * 4 + r] = acco[ct][r];
    __syncthreads();

    if (w == 0) {
        float L2 = Lred[0][n16] + Lred[1][n16] + Lred[2][n16] + Lred[3][n16];
        float rcpL2 = 1.f / L2;
        float gam = gamma[0];
#pragma unroll
        for (int ct = 0; ct < 4; ++ct) {
#pragma unroll
            for (int r = 0; r < 4; ++r) {
                int j = ct * 4 + r;
                float tot = Ared[0][lane][j] + Ared[1][lane][j] +
                            Ared[2][lane][j] + Ared[3][lane][j];
                int c = ct * 16 + 4 * g + r;
                size_t idx = ((size_t)(d * 64 + c)) * N_PIX + rb + n16;
                out[idx] = gam * tot * rcpL2 + x[idx];
            }
        }
    }
}

extern "C" void kernel_launch(void* const* d_in, const int* in_sizes, int n_in,
                              void* d_out, int out_size, void* d_ws, size_t ws_size,
                              hipStream_t stream) {
    const float* x     = (const float*)d_in[0];
    const float* atten = (const float*)d_in[1];
    const float* q_w   = (const float*)d_in[2];
    const float* q_b   = (const float*)d_in[3];
    const float* k_w   = (const float*)d_in[4];
    const float* k_b   = (const float*)d_in[5];
    const float* gamma = (const float*)d_in[6];
    float* out = (float*)d_out;

    char* ws = (char*)d_ws;
    const size_t MB = 1u << 20;
    unsigned short* qTp_hi = (unsigned short*)(ws + 0 * MB);   // [4][4096][32] bf16
    unsigned short* qTp_lo = (unsigned short*)(ws + 1 * MB);
    unsigned short* kTp_hi = (unsigned short*)(ws + 2 * MB);
    unsigned short* kTp_lo = (unsigned short*)(ws + 3 * MB);
    unsigned short* v_bf   = (unsigned short*)(ws + 4 * MB);   // [4][64][4096] bf16 (2 MB)
    float*          xp     = (float*)(ws + 8 * MB);            // [4][64][66][66] f32 (4.26 MB)

    hipLaunchKernelGGL(to_bf16_kernel, dim3(4096), dim3(256), 0, stream, x, v_bf);
    hipLaunchKernelGGL(pad_kernel, dim3(4356), dim3(256), 0, stream, x, xp);
    hipLaunchKernelGGL(conv_qk_kernel, dim3(2048), dim3(256), 0, stream,
                       xp, q_w, q_b, k_w, k_b, qTp_hi, qTp_lo, kTp_hi, kTp_lo);
    hipLaunchKernelGGL(attn_kernel, dim3(1024), dim3(256), 0, stream,
                       x, atten, gamma, qTp_hi, qTp_lo, kTp_hi, kTp_lo, v_bf, out);
}

// Round 4
// 530.811 us; speedup vs baseline: 1.2054x; 1.1366x over previous
//
#include <hip/hip_runtime.h>
#include <hip/hip_bf16.h>

typedef float  f32x4  __attribute__((ext_vector_type(4)));
typedef float  f32x4u __attribute__((ext_vector_type(4), aligned(4)));
typedef short  s16x4  __attribute__((ext_vector_type(4)));
typedef short  s16x8  __attribute__((ext_vector_type(8)));
typedef __bf16 bf16x8 __attribute__((ext_vector_type(8)));

#define N_PIX 4096

__device__ __forceinline__ unsigned short f2bf(float f) {
    __hip_bfloat16 h = __float2bfloat16(f);
    return *reinterpret_cast<unsigned short*>(&h);
}
__device__ __forceinline__ float bf2f(unsigned short u) {
    __hip_bfloat16 h;
    *reinterpret_cast<unsigned short*>(&h) = u;
    return __bfloat162float(h);
}

// ---- MFMA wrappers: prefer K=16 classic (layout certain), fall back to K=32 ----
#if __has_builtin(__builtin_amdgcn_mfma_f32_16x16x16bf16_1k)
#define USE_K16 1
#else
#define USE_K16 0
#endif

// Accumulate a K=32 block held as one 16B fragment per operand (k-slots permuted
// identically on A and B -> dot product unchanged).
__device__ __forceinline__ f32x4 mac_k32v(s16x8 a8, s16x8 b8, f32x4 c) {
#if USE_K16
    s16x4 alo = __builtin_shufflevector(a8, a8, 0, 1, 2, 3);
    s16x4 ahi = __builtin_shufflevector(a8, a8, 4, 5, 6, 7);
    s16x4 blo = __builtin_shufflevector(b8, b8, 0, 1, 2, 3);
    s16x4 bhi = __builtin_shufflevector(b8, b8, 4, 5, 6, 7);
    c = __builtin_amdgcn_mfma_f32_16x16x16bf16_1k(alo, blo, c, 0, 0, 0);
    c = __builtin_amdgcn_mfma_f32_16x16x16bf16_1k(ahi, bhi, c, 0, 0, 0);
#else
    c = __builtin_amdgcn_mfma_f32_16x16x32_bf16(__builtin_bit_cast(bf16x8, a8),
                                                __builtin_bit_cast(bf16x8, b8), c, 0, 0, 0);
#endif
    return c;
}

// ---- x -> bf16 copy (v operand for PV matmul), 4 elems/thread ----
__global__ __launch_bounds__(256) void to_bf16_kernel(const float* __restrict__ x,
                                                      unsigned short* __restrict__ v_bf) {
    int i = blockIdx.x * 256 + threadIdx.x;   // 262144 threads, 4 elems each
    f32x4 f = *(const f32x4*)(x + i * 4);
    s16x4 p;
    p[0] = (short)f2bf(f[0]); p[1] = (short)f2bf(f[1]);
    p[2] = (short)f2bf(f[2]); p[3] = (short)f2bf(f[3]);
    *(s16x4*)(v_bf + i * 4) = p;
}

// ---- zero-pad x into xp[4][64][66][66] ----
__global__ __launch_bounds__(256) void pad_kernel(const float* __restrict__ x,
                                                  float* __restrict__ xp) {
    int i = blockIdx.x * 256 + threadIdx.x;   // exactly 4*64*66*66 = 1115136 threads
    int xx = i % 66;
    int t  = i / 66;
    int yy = t % 66;
    int cd = t / 66;
    float v = 0.f;
    if (xx >= 1 && xx <= 64 && yy >= 1 && yy <= 64)
        v = x[(size_t)cd * 4096 + (yy - 1) * 64 + (xx - 1)];
    xp[i] = v;
}

// ---- conv3x3 (q and k): branch-free, dwordx4 loads, d-LSB XCD swizzle ----
__global__ __launch_bounds__(256) void conv_qk_kernel(
    const float* __restrict__ xp,
    const float* __restrict__ q_w, const float* __restrict__ q_b,
    const float* __restrict__ k_w, const float* __restrict__ k_b,
    unsigned short* __restrict__ qTp_hi, unsigned short* __restrict__ qTp_lo,
    unsigned short* __restrict__ kTp_hi, unsigned short* __restrict__ kTp_lo) {
    int bid = blockIdx.x;
    int d    = bid & 3;                                        // d in LSBs -> XCD affinity
    int rest = bid >> 2;
    int o  = __builtin_amdgcn_readfirstlane(rest & 31);        // uniform out-channel
    int yg = rest >> 5;                                        // 0..15
    int tid = threadIdx.x;
    int y   = yg * 4 + (tid >> 6);
    int col = tid & 63;
    const float* xc0 = xp + (size_t)d * (64 * 4356) + y * 66 + col;
    const float* wq = q_w + o * 576;
    const float* wk = k_w + o * 576;
    float aq0 = 0.f, aq1 = 0.f, aq2 = 0.f, ak0 = 0.f, ak1 = 0.f, ak2 = 0.f;
#pragma unroll 4
    for (int c = 0; c < 64; ++c) {
        const float* xc = xc0 + c * 4356;
        f32x4u r0 = *(const f32x4u*)(xc);
        f32x4u r1 = *(const f32x4u*)(xc + 66);
        f32x4u r2 = *(const f32x4u*)(xc + 132);
        const float* wqc = wq + c * 9;
        const float* wkc = wk + c * 9;
        aq0 = fmaf(wqc[0], r0[0], fmaf(wqc[1], r0[1], fmaf(wqc[2], r0[2], aq0)));
        aq1 = fmaf(wqc[3], r1[0], fmaf(wqc[4], r1[1], fmaf(wqc[5], r1[2], aq1)));
        aq2 = fmaf(wqc[6], r2[0], fmaf(wqc[7], r2[1], fmaf(wqc[8], r2[2], aq2)));
        ak0 = fmaf(wkc[0], r0[0], fmaf(wkc[1], r0[1], fmaf(wkc[2], r0[2], ak0)));
        ak1 = fmaf(wkc[3], r1[0], fmaf(wkc[4], r1[1], fmaf(wkc[5], r1[2], ak1)));
        ak2 = fmaf(wkc[6], r2[0], fmaf(wkc[7], r2[1], fmaf(wkc[8], r2[2], ak2)));
    }
    float aq = aq0 + aq1 + aq2 + q_b[o];
    float ak = ak0 + ak1 + ak2 + k_b[o];
    int n = y * 64 + col;
    size_t base = ((size_t)d * N_PIX + n) * 32 + o;
    unsigned short qh = f2bf(aq);
    unsigned short ql = f2bf(aq - bf2f(qh));
    unsigned short kh = f2bf(ak);
    unsigned short kl = f2bf(ak - bf2f(kh));
    qTp_hi[base] = qh; qTp_lo[base] = ql;
    kTp_hi[base] = kh; kTp_lo[base] = kl;
}

// ---- fused double-softmax attention: 4 waves/block, m-split across waves ----
// S^T orientation: MFMA D rows = m (4g+r within 16-tile), cols = n (lane&15).
// 16B fragment loads: lane (n16,g) holds k-slots [8g..8g+8) of each 32-chunk.
__global__ __launch_bounds__(256) void attn_kernel(
    const float* __restrict__ x, const float* __restrict__ atten,
    const float* __restrict__ gamma,
    const unsigned short* __restrict__ qTp_hi, const unsigned short* __restrict__ qTp_lo,
    const unsigned short* __restrict__ kTp_hi, const unsigned short* __restrict__ kTp_lo,
    const unsigned short* __restrict__ v_bf, float* __restrict__ out) {
    __shared__ __align__(16) unsigned short P_s[4][2][16][72];  // per-wave dbuf P tile
    __shared__ float Lred[4][16];
    __shared__ float Ared[4][64][17];

    int tid  = threadIdx.x;
    int lane = tid & 63;
    int w    = tid >> 6;
    int n16 = lane & 15;
    int g   = lane >> 4;
    int bid = blockIdx.x;
    int d   = bid & 3;               // d in LSBs -> XCD affinity
    int rb  = (bid >> 2) << 4;       // first of this block's 16 query rows
    int nrow = rb + n16;

    // q fragments (B operand), fixed for whole kernel
    size_t qrow = ((size_t)d * N_PIX + nrow) * 32;
    s16x8 qh8 = *(const s16x8*)(qTp_hi + qrow + 8 * g);
    s16x8 ql8 = *(const s16x8*)(qTp_lo + qrow + 8 * g);

    const unsigned short* kTh_d = kTp_hi + (size_t)d * N_PIX * 32;
    const unsigned short* kTl_d = kTp_lo + (size_t)d * N_PIX * 32;

    // ---------- phase A: L1 = sum_m exp(S - 40), wave w owns chunks (i*4+w) ----------
    float l1p = 0.f;
    for (int i = 0; i < 16; ++i) {
        int m0 = (i * 4 + w) * 64;
        s16x8 kh8[4], kl8[4];
#pragma unroll
        for (int t = 0; t < 4; ++t) {
            size_t krow = (size_t)(m0 + t * 16 + n16) * 32;
            kh8[t] = *(const s16x8*)(kTh_d + krow + 8 * g);
            kl8[t] = *(const s16x8*)(kTl_d + krow + 8 * g);
        }
#pragma unroll
        for (int t = 0; t < 4; ++t) {
            f32x4 s = {0.f, 0.f, 0.f, 0.f};
            s = mac_k32v(kh8[t], qh8, s);
            s = mac_k32v(kh8[t], ql8, s);
            s = mac_k32v(kl8[t], qh8, s);
            l1p += __expf(s[0] - 40.f) + __expf(s[1] - 40.f) +
                   __expf(s[2] - 40.f) + __expf(s[3] - 40.f);
        }
    }
    l1p += __shfl_xor(l1p, 16, 64);
    l1p += __shfl_xor(l1p, 32, 64);
    if (g == 0) Lred[w][n16] = l1p;
    __syncthreads();
    float L1 = Lred[0][n16] + Lred[1][n16] + Lred[2][n16] + Lred[3][n16];
    float rcpL1 = 1.f / L1;

    // ---------- phase B: second softmax (fixed shift 8) + PV accumulation ----------
    const float* arow = atten + ((size_t)d << 24) + (size_t)nrow * N_PIX;
    const unsigned short* v_d = v_bf + (size_t)d * 64 * N_PIX;
    float l2p = 0.f;
    f32x4 acco[4];
#pragma unroll
    for (int ct = 0; ct < 4; ++ct) acco[ct] = f32x4{0.f, 0.f, 0.f, 0.f};

    for (int i = 0; i < 16; ++i) {
        int m0 = (i * 4 + w) * 64;
        int buf = i & 1;
        // issue longest-latency loads first (atten from HBM), then k from L2
        f32x4 av4[4];
#pragma unroll
        for (int t = 0; t < 4; ++t)
            av4[t] = *(const f32x4*)&arow[m0 + t * 16 + 4 * g];
        s16x8 kh8[4], kl8[4];
#pragma unroll
        for (int t = 0; t < 4; ++t) {
            size_t krow = (size_t)(m0 + t * 16 + n16) * 32;
            kh8[t] = *(const s16x8*)(kTh_d + krow + 8 * g);
            kl8[t] = *(const s16x8*)(kTl_d + krow + 8 * g);
        }
#pragma unroll
        for (int t = 0; t < 4; ++t) {
            f32x4 s = {0.f, 0.f, 0.f, 0.f};
            s = mac_k32v(kh8[t], qh8, s);
            s = mac_k32v(kh8[t], ql8, s);
            s = mac_k32v(kl8[t], qh8, s);
            s16x4 pp;
#pragma unroll
            for (int r = 0; r < 4; ++r) {
                float attn1 = __expf(s[r] - 40.f) * rcpL1;
                float p = __expf(attn1 + av4[t][r] - 8.f);
                l2p += p;
                pp[r] = (short)f2bf(p);
            }
            *(s16x4*)&P_s[w][buf][n16][t * 16 + 4 * g] = pp;  // packed 8B write
        }
        asm volatile("" ::: "memory");   // order this buf's LDS writes before its reads

        // PV: out[c][n] += sum_m P[n][m] * v[c][m], two K=32 halves
#pragma unroll
        for (int h = 0; h < 2; ++h) {
            s16x8 p8 = *(const s16x8*)&P_s[w][buf][n16][h * 32 + 8 * g];
#pragma unroll
            for (int ct = 0; ct < 4; ++ct) {
                const unsigned short* vr = v_d + (size_t)(ct * 16 + n16) * N_PIX + m0 + h * 32;
                s16x8 v8 = *(const s16x8*)(vr + 8 * g);
                acco[ct] = mac_k32v(v8, p8, acco[ct]);
            }
        }
        // no trailing fence: next iteration writes the other buffer
    }

    // ---------- cross-wave reduction + epilogue ----------
    __syncthreads();
    l2p += __shfl_xor(l2p, 16, 64);
    l2p += __shfl_xor(l2p, 32, 64);
    if (g == 0) Lred[w][n16] = l2p;
#pragma unroll
    for (int ct = 0; ct < 4; ++ct)
#pragma unroll
        for (int r = 0; r < 4; ++r)
            Ared[w][lane][ct * 4 + r] = acco[ct][r];
    __syncthreads();

    if (w == 0) {
        float L2 = Lred[0][n16] + Lred[1][n16] + Lred[2][n16] + Lred[3][n16];
        float rcpL2 = 1.f / L2;
        float gam = gamma[0];
#pragma unroll
        for (int ct = 0; ct < 4; ++ct) {
#pragma unroll
            for (int r = 0; r < 4; ++r) {
                int j = ct * 4 + r;
                float tot = Ared[0][lane][j] + Ared[1][lane][j] +
                            Ared[2][lane][j] + Ared[3][lane][j];
                int c = ct * 16 + 4 * g + r;
                size_t idx = ((size_t)(d * 64 + c)) * N_PIX + rb + n16;
                out[idx] = gam * tot * rcpL2 + x[idx];
            }
        }
    }
}

extern "C" void kernel_launch(void* const* d_in, const int* in_sizes, int n_in,
                              void* d_out, int out_size, void* d_ws, size_t ws_size,
                              hipStream_t stream) {
    const float* x     = (const float*)d_in[0];
    const float* atten = (const float*)d_in[1];
    const float* q_w   = (const float*)d_in[2];
    const float* q_b   = (const float*)d_in[3];
    const float* k_w   = (const float*)d_in[4];
    const float* k_b   = (const float*)d_in[5];
    const float* gamma = (const float*)d_in[6];
    float* out = (float*)d_out;

    char* ws = (char*)d_ws;
    const size_t MB = 1u << 20;
    unsigned short* qTp_hi = (unsigned short*)(ws + 0 * MB);   // [4][4096][32] bf16
    unsigned short* qTp_lo = (unsigned short*)(ws + 1 * MB);
    unsigned short* kTp_hi = (unsigned short*)(ws + 2 * MB);
    unsigned short* kTp_lo = (unsigned short*)(ws + 3 * MB);
    unsigned short* v_bf   = (unsigned short*)(ws + 4 * MB);   // [4][64][4096] bf16 (2 MB)
    float*          xp     = (float*)(ws + 8 * MB);            // [4][64][66][66] f32 (4.26 MB)

    hipLaunchKernelGGL(to_bf16_kernel, dim3(1024), dim3(256), 0, stream, x, v_bf);
    hipLaunchKernelGGL(pad_kernel, dim3(4356), dim3(256), 0, stream, x, xp);
    hipLaunchKernelGGL(conv_qk_kernel, dim3(2048), dim3(256), 0, stream,
                       xp, q_w, q_b, k_w, k_b, qTp_hi, qTp_lo, kTp_hi, kTp_lo);
    hipLaunchKernelGGL(attn_kernel, dim3(1024), dim3(256), 0, stream,
                       x, atten, gamma, qTp_hi, qTp_lo, kTp_hi, kTp_lo, v_bf, out);
}

// Round 5
// 500.746 us; speedup vs baseline: 1.2778x; 1.0600x over previous
//
#include <hip/hip_runtime.h>
#include <hip/hip_bf16.h>

typedef float  f32x4  __attribute__((ext_vector_type(4)));
typedef float  f32x4u __attribute__((ext_vector_type(4), aligned(4)));
typedef short  s16x4  __attribute__((ext_vector_type(4)));
typedef short  s16x8  __attribute__((ext_vector_type(8)));
typedef __bf16 bf16x8 __attribute__((ext_vector_type(8)));

#define N_PIX 4096

__device__ __forceinline__ unsigned short f2bf(float f) {
    __hip_bfloat16 h = __float2bfloat16(f);
    return *reinterpret_cast<unsigned short*>(&h);
}
__device__ __forceinline__ float bf2f(unsigned short u) {
    __hip_bfloat16 h;
    *reinterpret_cast<unsigned short*>(&h) = u;
    return __bfloat162float(h);
}

// async global->LDS, 16B per lane (1 KB contiguous per wave-instr)
__device__ __forceinline__ void gload_lds16(const void* g, void* l) {
    __builtin_amdgcn_global_load_lds(
        (const __attribute__((address_space(1))) unsigned int*)g,
        (__attribute__((address_space(3))) unsigned int*)l,
        16, 0, 0);
}

// ---- MFMA wrappers: prefer K=16 classic (layout certain), fall back to K=32 ----
#if __has_builtin(__builtin_amdgcn_mfma_f32_16x16x16bf16_1k)
#define USE_K16 1
#else
#define USE_K16 0
#endif

__device__ __forceinline__ f32x4 mac_k32v(s16x8 a8, s16x8 b8, f32x4 c) {
#if USE_K16
    s16x4 alo = __builtin_shufflevector(a8, a8, 0, 1, 2, 3);
    s16x4 ahi = __builtin_shufflevector(a8, a8, 4, 5, 6, 7);
    s16x4 blo = __builtin_shufflevector(b8, b8, 0, 1, 2, 3);
    s16x4 bhi = __builtin_shufflevector(b8, b8, 4, 5, 6, 7);
    c = __builtin_amdgcn_mfma_f32_16x16x16bf16_1k(alo, blo, c, 0, 0, 0);
    c = __builtin_amdgcn_mfma_f32_16x16x16bf16_1k(ahi, bhi, c, 0, 0, 0);
#else
    c = __builtin_amdgcn_mfma_f32_16x16x32_bf16(__builtin_bit_cast(bf16x8, a8),
                                                __builtin_bit_cast(bf16x8, b8), c, 0, 0, 0);
#endif
    return c;
}

// ---- x -> bf16 copy (v operand for PV matmul), 4 elems/thread ----
__global__ __launch_bounds__(256) void to_bf16_kernel(const float* __restrict__ x,
                                                      unsigned short* __restrict__ v_bf) {
    int i = blockIdx.x * 256 + threadIdx.x;
    f32x4 f = *(const f32x4*)(x + i * 4);
    s16x4 p;
    p[0] = (short)f2bf(f[0]); p[1] = (short)f2bf(f[1]);
    p[2] = (short)f2bf(f[2]); p[3] = (short)f2bf(f[3]);
    *(s16x4*)(v_bf + i * 4) = p;
}

// ---- zero-pad x into xp[4][64][66][66] ----
__global__ __launch_bounds__(256) void pad_kernel(const float* __restrict__ x,
                                                  float* __restrict__ xp) {
    int i = blockIdx.x * 256 + threadIdx.x;
    int xx = i % 66;
    int t  = i / 66;
    int yy = t % 66;
    int cd = t / 66;
    float v = 0.f;
    if (xx >= 1 && xx <= 64 && yy >= 1 && yy <= 64)
        v = x[(size_t)cd * 4096 + (yy - 1) * 64 + (xx - 1)];
    xp[i] = v;
}

// ---- conv3x3 (q and k): branch-free, dwordx4 loads, d-LSB XCD swizzle ----
__global__ __launch_bounds__(256) void conv_qk_kernel(
    const float* __restrict__ xp,
    const float* __restrict__ q_w, const float* __restrict__ q_b,
    const float* __restrict__ k_w, const float* __restrict__ k_b,
    unsigned short* __restrict__ qTp_hi, unsigned short* __restrict__ qTp_lo,
    unsigned short* __restrict__ kTp_hi, unsigned short* __restrict__ kTp_lo) {
    int bid = blockIdx.x;
    int d    = bid & 3;
    int rest = bid >> 2;
    int o  = __builtin_amdgcn_readfirstlane(rest & 31);
    int yg = rest >> 5;
    int tid = threadIdx.x;
    int y   = yg * 4 + (tid >> 6);
    int col = tid & 63;
    const float* xc0 = xp + (size_t)d * (64 * 4356) + y * 66 + col;
    const float* wq = q_w + o * 576;
    const float* wk = k_w + o * 576;
    float aq0 = 0.f, aq1 = 0.f, aq2 = 0.f, ak0 = 0.f, ak1 = 0.f, ak2 = 0.f;
#pragma unroll 4
    for (int c = 0; c < 64; ++c) {
        const float* xc = xc0 + c * 4356;
        f32x4u r0 = *(const f32x4u*)(xc);
        f32x4u r1 = *(const f32x4u*)(xc + 66);
        f32x4u r2 = *(const f32x4u*)(xc + 132);
        const float* wqc = wq + c * 9;
        const float* wkc = wk + c * 9;
        aq0 = fmaf(wqc[0], r0[0], fmaf(wqc[1], r0[1], fmaf(wqc[2], r0[2], aq0)));
        aq1 = fmaf(wqc[3], r1[0], fmaf(wqc[4], r1[1], fmaf(wqc[5], r1[2], aq1)));
        aq2 = fmaf(wqc[6], r2[0], fmaf(wqc[7], r2[1], fmaf(wqc[8], r2[2], aq2)));
        ak0 = fmaf(wkc[0], r0[0], fmaf(wkc[1], r0[1], fmaf(wkc[2], r0[2], ak0)));
        ak1 = fmaf(wkc[3], r1[0], fmaf(wkc[4], r1[1], fmaf(wkc[5], r1[2], ak1)));
        ak2 = fmaf(wkc[6], r2[0], fmaf(wkc[7], r2[1], fmaf(wkc[8], r2[2], ak2)));
    }
    float aq = aq0 + aq1 + aq2 + q_b[o];
    float ak = ak0 + ak1 + ak2 + k_b[o];
    int n = y * 64 + col;
    size_t base = ((size_t)d * N_PIX + n) * 32 + o;
    unsigned short qh = f2bf(aq);
    unsigned short ql = f2bf(aq - bf2f(qh));
    unsigned short kh = f2bf(ak);
    unsigned short kl = f2bf(ak - bf2f(kh));
    qTp_hi[base] = qh; qTp_lo[base] = ql;
    kTp_hi[base] = kh; kTp_lo[base] = kl;
}

// ---- fused double-softmax attention ----
// 4 waves/block; wave w owns m-chunk (i*4+w)*64 of each 256-wide tile column.
// atten staged block-cooperatively via global_load_lds (1KB bursts), double-buffered,
// XOR-swizzled (source-side lane^(row&7), read-side chunk^(n16&7)).
__global__ __launch_bounds__(256, 4) void attn_kernel(
    const float* __restrict__ x, const float* __restrict__ atten,
    const float* __restrict__ gamma,
    const unsigned short* __restrict__ qTp_hi, const unsigned short* __restrict__ qTp_lo,
    const unsigned short* __restrict__ kTp_hi, const unsigned short* __restrict__ kTp_lo,
    const unsigned short* __restrict__ v_bf, float* __restrict__ out) {
    __shared__ __align__(16) char smem[40960];
    float (*tile)[16][256]       = (float (*)[16][256])smem;                         // 32 KB
    unsigned short (*P_s)[16][64] = (unsigned short (*)[16][64])(smem + 32768);      // 8 KB
    float (*Lred)[16]            = (float (*)[16])(smem + 32768);                    // overlays P_s
    float (*Ared)[64][17]        = (float (*)[64][17])smem;                          // overlays tile

    int tid  = threadIdx.x;
    int lane = tid & 63;
    int w    = tid >> 6;
    int n16  = lane & 15;
    int g    = lane >> 4;
    int bid  = blockIdx.x;
    int d    = bid & 3;              // d in LSBs -> XCD affinity
    int rb   = (bid >> 2) << 4;      // first of this block's 16 query rows
    int nrow = rb + n16;

    size_t qrow = ((size_t)d * N_PIX + nrow) * 32;
    s16x8 qh8 = *(const s16x8*)(qTp_hi + qrow + 8 * g);
    s16x8 ql8 = *(const s16x8*)(qTp_lo + qrow + 8 * g);

    const unsigned short* kTh_d = kTp_hi + (size_t)d * N_PIX * 32;
    const unsigned short* kTl_d = kTp_lo + (size_t)d * N_PIX * 32;
    const float* atten_d = atten + ((size_t)d << 24);

    // ---------- phase A: L1 = sum_m exp(S - 40) ----------
    float l1p = 0.f;
    for (int i = 0; i < 16; ++i) {
        int m0 = (i * 4 + w) * 64;
        s16x8 kh8[4], kl8[4];
#pragma unroll
        for (int t = 0; t < 4; ++t) {
            size_t krow = (size_t)(m0 + t * 16 + n16) * 32;
            kh8[t] = *(const s16x8*)(kTh_d + krow + 8 * g);
            kl8[t] = *(const s16x8*)(kTl_d + krow + 8 * g);
        }
#pragma unroll
        for (int t = 0; t < 4; ++t) {
            f32x4 s = {0.f, 0.f, 0.f, 0.f};
            s = mac_k32v(kh8[t], qh8, s);
            s = mac_k32v(kh8[t], ql8, s);
            s = mac_k32v(kl8[t], qh8, s);
            l1p += __expf(s[0] - 40.f) + __expf(s[1] - 40.f) +
                   __expf(s[2] - 40.f) + __expf(s[3] - 40.f);
        }
    }
    // issue atten tile 0 (overlaps the L1 reduction + barrier)
#pragma unroll
    for (int j = 0; j < 4; ++j) {
        int r = 4 * w + j;
        const float* gp = atten_d + (size_t)(rb + r) * N_PIX + ((lane ^ (r & 7)) << 2);
        gload_lds16(gp, (void*)&tile[0][r][0]);
    }
    l1p += __shfl_xor(l1p, 16, 64);
    l1p += __shfl_xor(l1p, 32, 64);
    if (g == 0) Lred[w][n16] = l1p;
    __syncthreads();
    float rcpL1 = 1.f / (Lred[0][n16] + Lred[1][n16] + Lred[2][n16] + Lred[3][n16]);

    // ---------- phase B: second softmax (fixed shift 8) + PV ----------
    const unsigned short* v_d = v_bf + (size_t)d * 64 * N_PIX;
    float l2p = 0.f;
    f32x4 acco[4];
#pragma unroll
    for (int ct = 0; ct < 4; ++ct) acco[ct] = f32x4{0.f, 0.f, 0.f, 0.f};

    for (int i = 0; i < 16; ++i) {
        int m0 = (i * 4 + w) * 64;
        // S = q^T k for this wave's 64-m chunk
        s16x8 kh8[4], kl8[4];
#pragma unroll
        for (int t = 0; t < 4; ++t) {
            size_t krow = (size_t)(m0 + t * 16 + n16) * 32;
            kh8[t] = *(const s16x8*)(kTh_d + krow + 8 * g);
            kl8[t] = *(const s16x8*)(kTl_d + krow + 8 * g);
        }
        f32x4 sArr[4];
#pragma unroll
        for (int t = 0; t < 4; ++t) {
            f32x4 s = {0.f, 0.f, 0.f, 0.f};
            s = mac_k32v(kh8[t], qh8, s);
            s = mac_k32v(kh8[t], ql8, s);
            s = mac_k32v(kl8[t], qh8, s);
            sArr[t] = s;
        }
        // drain tile(i) gl_lds; all waves ready
        asm volatile("s_waitcnt vmcnt(0)" ::: "memory");
        __builtin_amdgcn_s_barrier();
        // issue tile(i+1) (safe: all waves past barrier => done reading this buf)
        if (i < 15) {
#pragma unroll
            for (int j = 0; j < 4; ++j) {
                int r = 4 * w + j;
                const float* gp = atten_d + (size_t)(rb + r) * N_PIX + (i + 1) * 256 +
                                  ((lane ^ (r & 7)) << 2);
                gload_lds16(gp, (void*)&tile[(i + 1) & 1][r][0]);
            }
        }
        // softmax from tile[i&1] (swizzled read), write P (swizzled)
        const char* trow = (const char*)&tile[i & 1][n16][0];
        char* prow = (char*)&P_s[w][n16][0];
#pragma unroll
        for (int t = 0; t < 4; ++t) {
            int chunk = 16 * w + 4 * t + g;
            f32x4 av = *(const f32x4*)(trow + ((chunk ^ (n16 & 7)) << 4));
            s16x4 pp;
#pragma unroll
            for (int r = 0; r < 4; ++r) {
                float attn1 = __expf(sArr[t][r] - 40.f) * rcpL1;
                float p = __expf(attn1 + av[r] - 8.f);
                l2p += p;
                pp[r] = (short)f2bf(p);
            }
            *(s16x4*)(prow + ((t * 32 + 8 * g) ^ ((n16 & 7) << 4))) = pp;
        }
        asm volatile("" ::: "memory");   // P writes before P reads (same wave)

        // PV: out[c][n] += sum_m P[n][m] * v[c][m]
#pragma unroll
        for (int h = 0; h < 2; ++h) {
            s16x8 p8 = *(const s16x8*)(prow + ((h * 64 + 16 * g) ^ ((n16 & 7) << 4)));
#pragma unroll
            for (int ct = 0; ct < 4; ++ct) {
                const unsigned short* vr = v_d + (size_t)(ct * 16 + n16) * N_PIX + m0 + h * 32;
                s16x8 v8 = *(const s16x8*)(vr + 8 * g);
                acco[ct] = mac_k32v(v8, p8, acco[ct]);
            }
        }
        asm volatile("" ::: "memory");   // P reads before next iter's P writes
    }

    // ---------- cross-wave reduction + epilogue ----------
    l2p += __shfl_xor(l2p, 16, 64);
    l2p += __shfl_xor(l2p, 32, 64);
    __syncthreads();                     // tile + P_s dead; safe to overlay
    if (g == 0) Lred[w][n16] = l2p;
#pragma unroll
    for (int ct = 0; ct < 4; ++ct)
#pragma unroll
        for (int r = 0; r < 4; ++r)
            Ared[w][lane][ct * 4 + r] = acco[ct][r];
    __syncthreads();

    if (w == 0) {
        float L2 = Lred[0][n16] + Lred[1][n16] + Lred[2][n16] + Lred[3][n16];
        float rcpL2 = 1.f / L2;
        float gam = gamma[0];
#pragma unroll
        for (int ct = 0; ct < 4; ++ct) {
#pragma unroll
            for (int r = 0; r < 4; ++r) {
                int j = ct * 4 + r;
                float tot = Ared[0][lane][j] + Ared[1][lane][j] +
                            Ared[2][lane][j] + Ared[3][lane][j];
                int c = ct * 16 + 4 * g + r;
                size_t idx = ((size_t)(d * 64 + c)) * N_PIX + rb + n16;
                out[idx] = gam * tot * rcpL2 + x[idx];
            }
        }
    }
}

extern "C" void kernel_launch(void* const* d_in, const int* in_sizes, int n_in,
                              void* d_out, int out_size, void* d_ws, size_t ws_size,
                              hipStream_t stream) {
    const float* x     = (const float*)d_in[0];
    const float* atten = (const float*)d_in[1];
    const float* q_w   = (const float*)d_in[2];
    const float* q_b   = (const float*)d_in[3];
    const float* k_w   = (const float*)d_in[4];
    const float* k_b   = (const float*)d_in[5];
    const float* gamma = (const float*)d_in[6];
    float* out = (float*)d_out;

    char* ws = (char*)d_ws;
    const size_t MB = 1u << 20;
    unsigned short* qTp_hi = (unsigned short*)(ws + 0 * MB);   // [4][4096][32] bf16
    unsigned short* qTp_lo = (unsigned short*)(ws + 1 * MB);
    unsigned short* kTp_hi = (unsigned short*)(ws + 2 * MB);
    unsigned short* kTp_lo = (unsigned short*)(ws + 3 * MB);
    unsigned short* v_bf   = (unsigned short*)(ws + 4 * MB);   // [4][64][4096] bf16 (2 MB)
    float*          xp     = (float*)(ws + 8 * MB);            // [4][64][66][66] f32 (4.26 MB)

    hipLaunchKernelGGL(to_bf16_kernel, dim3(1024), dim3(256), 0, stream, x, v_bf);
    hipLaunchKernelGGL(pad_kernel, dim3(4356), dim3(256), 0, stream, x, xp);
    hipLaunchKernelGGL(conv_qk_kernel, dim3(2048), dim3(256), 0, stream,
                       xp, q_w, q_b, k_w, k_b, qTp_hi, qTp_lo, kTp_hi, kTp_lo);
    hipLaunchKernelGGL(attn_kernel, dim3(1024), dim3(256), 0, stream,
                       x, atten, gamma, qTp_hi, qTp_lo, kTp_hi, kTp_lo, v_bf, out);
}